// Round 5
// baseline (2872.061 us; speedup 1.0000x reference)
//
#include <hip/hip_runtime.h>
#include <math.h>

constexpr int B_ = 2, C_ = 32, NS = 32, NZ = 96, NX = 96;
constexpr int KS = 16, KZ = 24, KX = 12;          // kept mode counts (s, z, x)
constexpr int NPTS = B_ * NS * NZ * NX;           // 589824
constexpr int CHS  = NS * NZ * NX;                // 294912 (per-channel stride)
constexpr size_t HSIZE = (size_t)B_ * C_ * CHS;   // 18,874,368 floats

constexpr size_t FX_C  = (size_t)B_ * C_ * NS * KX * NZ;  // 2,359,296 cplx (gz)
constexpr size_t FZX_C = (size_t)B_ * C_ * KZ * KX * NS;  //   589,824 cplx (fzx/gs)
constexpr size_t FS_C  = (size_t)B_ * C_ * KS * KZ * KX;  //   294,912 cplx

// workspace offsets (floats). gs overlays FZX, gz overlays FX (sizes match).
constexpr size_t OFF_HA   = 0;
constexpr size_t OFF_HB   = OFF_HA + HSIZE;
constexpr size_t OFF_FX   = OFF_HB + HSIZE;
constexpr size_t OFF_FZX  = OFF_FX + 2 * FX_C;
constexpr size_t OFF_FS   = OFF_FZX + 2 * FZX_C;
constexpr size_t OFF_G    = OFF_FS + 2 * FS_C;
constexpr size_t OFF_ST   = OFF_G + 2 * FS_C;     // 4 layers x (sum[32], sumsq[32])
constexpr size_t OFF_SC   = OFF_ST + 256;         // 4 layers x (scale[32], shift[32])
constexpr size_t OFF_TWXF = OFF_SC + 256;         // [x=96][k=12] cplx, e^{-i}
constexpr size_t OFF_TWZF = OFF_TWXF + 2 * 96 * 12;   // [z=96][k=24]
constexpr size_t OFF_TWSF = OFF_TWZF + 2 * 96 * 24;   // [s=32][k=16], includes 1/294912
constexpr size_t OFF_TWSI = OFF_TWSF + 2 * 32 * 16;   // [k=16][s=32] cplx, e^{+i}
constexpr size_t OFF_TWZI = OFF_TWSI + 2 * 16 * 32;   // [k=24][z=96]
constexpr size_t OFF_TWXI = OFF_TWZI + 2 * 24 * 96;   // [k=12][x=96]

__global__ void k_init_tw(float* ws) {
  const double TWO_PI = 6.283185307179586476925286766559;
  int t = threadIdx.x;
  float2* twxf = (float2*)(ws + OFF_TWXF);
  for (int i = t; i < 96 * 12; i += 256) {
    int x = i / 12, k = i % 12;
    double a = -TWO_PI * (double)((k * x) % 96) / 96.0;
    twxf[i] = make_float2((float)cos(a), (float)sin(a));
  }
  float2* twzf = (float2*)(ws + OFF_TWZF);
  for (int i = t; i < 96 * 24; i += 256) {
    int z = i / 24, k = i % 24;
    double a = -TWO_PI * (double)((k * z) % 96) / 96.0;
    twzf[i] = make_float2((float)cos(a), (float)sin(a));
  }
  float2* twsf = (float2*)(ws + OFF_TWSF);
  const double SC = 1.0 / (double)(NS * NZ * NX);  // fftn norm='forward'
  for (int i = t; i < 32 * 16; i += 256) {
    int s = i / 16, k = i % 16;
    int f = (k < 8) ? k : k + 16;                  // s-modes 0..7, 24..31
    double a = -TWO_PI * (double)((f * s) % 32) / 32.0;
    twsf[i] = make_float2((float)(cos(a) * SC), (float)(sin(a) * SC));
  }
  float2* twsi = (float2*)(ws + OFF_TWSI);
  for (int i = t; i < 16 * 32; i += 256) {
    int k = i / 32, s = i % 32;
    int f = (k < 8) ? k : k + 16;
    double a = TWO_PI * (double)((f * s) % 32) / 32.0;
    twsi[i] = make_float2((float)cos(a), (float)sin(a));
  }
  float2* twzi = (float2*)(ws + OFF_TWZI);
  for (int i = t; i < 24 * 96; i += 256) {
    int k = i / 96, z = i % 96;
    int f = (k < 12) ? k : k + 72;                 // z-modes 0..11, 84..95
    double a = TWO_PI * (double)((f * z) % 96) / 96.0;
    twzi[i] = make_float2((float)cos(a), (float)sin(a));
  }
  float2* twxi = (float2*)(ws + OFF_TWXI);
  for (int i = t; i < 12 * 96; i += 256) {
    int k = i / 96, x = i % 96;
    double a = TWO_PI * (double)((k * x) % 96) / 96.0;
    twxi[i] = make_float2((float)cos(a), (float)sin(a));
  }
}

__global__ void k_zero_stats(float* st) {
  st[threadIdx.x] = 0.f;   // 256 threads, 256 floats
}

// h[b][c][s][z][x] = x0*w[0][c] + x1*w[1][c] + b[c]
__global__ void k_fc0(const float* __restrict__ xin, const float* __restrict__ w,
                      const float* __restrict__ bias, float* __restrict__ h) {
  int pt = blockIdx.x * 256 + threadIdx.x;
  float2 xv = ((const float2*)xin)[pt];
  size_t base = (size_t)(pt / CHS) * C_ * CHS + (pt % CHS);
  for (int c = 0; c < C_; ++c)
    h[base + (size_t)c * CHS] = xv.x * w[c] + xv.y * w[C_ + c] + bias[c];
}

// Fused dftx+dftz. block = (b,c,s). Stage BN(h) plane in LDS (coalesced, +97
// pad), dftx with 6 complex reg-accumulators per thread + SCALAR twiddles
// (half = t>>7 is wave-uniform), dftz with dual accumulators.
// Output fzx[bcs][kz*12+kx] contiguous per block.
__global__ __launch_bounds__(256) void k_fwd(const float* __restrict__ h, float2* __restrict__ fzx,
                      const float2* __restrict__ twxf, const float2* __restrict__ twzf,
                      const float* __restrict__ sc, int use_bn) {
  __shared__ float  sh_h[96 * 97];     // 37.2 KB
  __shared__ float2 sh_fx[96 * 12];    // 9 KB  [z][kx]
  int t = threadIdx.x;
  int bcs = blockIdx.x;               // 2048 = 64 bc * 32 s
  int s = bcs & 31;
  int bc = bcs >> 5;
  int c = bc & 31;
  float scale = use_bn ? sc[c] : 1.f;
  float shift = use_bn ? sc[32 + c] : 0.f;
  float lk = use_bn ? 0.1f : 1.0f;
  const float* hp = h + (size_t)bc * CHS + (size_t)s * (NZ * NX);
  for (int i = t; i < NZ * NX; i += 256) {
    float v = hp[i];                   // coalesced row-major
    v = v * scale + shift;
    v = v >= 0.f ? v : v * lk;
    sh_h[(i / 96) * 97 + (i % 96)] = v;
  }
  __syncthreads();
  // dftx: waves 0-1 -> kx 0..5, waves 2-3 -> kx 6..11; z = t&127 (<96 active)
  {
    int half = t >> 7;                 // wave-uniform
    int z = t & 127;
    if (z < 96) {
      float ar[6], ai[6];
      #pragma unroll
      for (int j = 0; j < 6; ++j) { ar[j] = 0.f; ai[j] = 0.f; }
      const float2* twx = twxf + half * 6;
      const float* row = sh_h + z * 97;
      for (int x = 0; x < 96; ++x) {
        float v = row[x];              // 1 ds_read per 12 FMAs
        #pragma unroll
        for (int j = 0; j < 6; ++j) {
          float2 w = twx[x * 12 + j];  // wave-uniform -> s_load (K$-hot)
          ar[j] += v * w.x; ai[j] += v * w.y;
        }
      }
      #pragma unroll
      for (int j = 0; j < 6; ++j)
        sh_fx[z * 12 + half * 6 + j] = make_float2(ar[j], ai[j]);
    }
  }
  __syncthreads();
  // dftz: item = (kz,kx), 288 items; dual accumulators, tw L1-hot vector loads
  float2* outp = fzx + (size_t)bcs * 288;
  for (int it = t; it < 288; it += 256) {
    int kx = it % 12, kz = it / 12;
    float ar0 = 0.f, ai0 = 0.f, ar1 = 0.f, ai1 = 0.f;
    for (int z = 0; z < 96; z += 2) {
      float2 v0 = sh_fx[z * 12 + kx];
      float2 w0 = twzf[z * 24 + kz];
      float2 v1 = sh_fx[(z + 1) * 12 + kx];
      float2 w1 = twzf[(z + 1) * 24 + kz];
      ar0 += v0.x * w0.x - v0.y * w0.y;
      ai0 += v0.x * w0.y + v0.y * w0.x;
      ar1 += v1.x * w1.x - v1.y * w1.y;
      ai1 += v1.x * w1.y + v1.y * w1.x;
    }
    outp[it] = make_float2(ar0 + ar1, ai0 + ai1);   // coalesced
  }
}

// Fs[bc][ks*288+kzkx] = sum_s Fzx[bc][s][kzkx] * tw; thread per output.
__global__ __launch_bounds__(256) void k_dfts(const float2* __restrict__ fzx, float2* __restrict__ fs,
                       const float2* __restrict__ tw) {
  int tid = blockIdx.x * 256 + threadIdx.x;   // 294,912
  int kzkx = tid % 288;
  int ks = (tid / 288) & 15;
  int bc = tid / 4608;
  const float2* src = fzx + (size_t)bc * (32 * 288) + kzkx;
  float ar = 0.f, ai = 0.f;
  #pragma unroll 8
  for (int s = 0; s < 32; ++s) {
    float2 v = src[s * 288];
    float2 w = tw[s * 16 + ks];
    ar += v.x * w.x - v.y * w.y;
    ai += v.x * w.y + v.y * w.x;
  }
  fs[(size_t)bc * 4608 + ks * 288 + kzkx] = make_float2(ar, ai);
}

// G[b][o][fidx] = sum_i Fs[b][i][fidx] * w[l,q,i,o,mode]; lanes = consecutive modes
__global__ __launch_bounds__(256) void k_mix(const float2* __restrict__ fs, const float* __restrict__ spec,
                      int l, float2* __restrict__ g) {
  int tid = blockIdx.x * 256 + threadIdx.x;   // 147,456 = 4q * 32o * 1152m
  int m = tid % 1152;
  int o = (tid / 1152) & 31;
  int q = tid / 36864;
  int m1 = m / 144, r = m - m1 * 144, m2 = r / 12, m3 = r - m2 * 12;
  int ks = m1 + (q & 1) * 8;
  int kz = m2 + ((q >> 1) & 1) * 12;
  int fidx = (ks * KZ + kz) * KX + m3;
  const float2* w2 = (const float2*)spec;
  size_t widx = ((size_t)(l * 4 + q) * 1024 + o) * 1152 + m;   // + i*36864 per i
  const float2* f0 = fs + fidx;                                 // + i*4608 per i
  const float2* f1 = fs + (size_t)C_ * 4608 + fidx;
  float a0r = 0.f, a0i = 0.f, a1r = 0.f, a1i = 0.f;
  #pragma unroll 4
  for (int i = 0; i < C_; ++i) {
    float2 w = w2[widx];  widx += 36864;
    float2 v0 = f0[(size_t)i * 4608];
    float2 v1 = f1[(size_t)i * 4608];
    a0r += v0.x * w.x - v0.y * w.y;  a0i += v0.x * w.y + v0.y * w.x;
    a1r += v1.x * w.x - v1.y * w.y;  a1i += v1.x * w.y + v1.y * w.x;
  }
  g[(size_t)o * 4608 + fidx] = make_float2(a0r, a0i);
  g[(size_t)(C_ + o) * 4608 + fidx] = make_float2(a1r, a1i);
}

// Gs[bo][s][kzkx] = sum_ks G[bo][ks*288+kzkx] * tw; thread per output.
__global__ __launch_bounds__(256) void k_idfts(const float2* __restrict__ g, float2* __restrict__ gs,
                        const float2* __restrict__ tw) {
  int tid = blockIdx.x * 256 + threadIdx.x;   // 589,824
  int kzkx = tid % 288;
  int s = (tid / 288) & 31;
  int bo = tid / 9216;
  const float2* src = g + (size_t)bo * 4608 + kzkx;
  float ar = 0.f, ai = 0.f;
  #pragma unroll
  for (int ks = 0; ks < 16; ++ks) {
    float2 v = src[ks * 288];
    float2 w = tw[ks * 32 + s];
    ar += v.x * w.x - v.y * w.y;
    ai += v.x * w.y + v.y * w.x;
  }
  gs[((size_t)bo * 32 + s) * 288 + kzkx] = make_float2(ar, ai);
}

// Gz[bo][s][z][kx] = sum_kz Gs[bo][s][kz*12+kx] * tw; thread per output.
__global__ __launch_bounds__(256) void k_idftz(const float2* __restrict__ gs, float2* __restrict__ gz,
                        const float2* __restrict__ tw) {
  int tid = blockIdx.x * 256 + threadIdx.x;   // 2,359,296
  int kx = tid % 12;
  int z = (tid / 12) % 96;
  int s = (tid / 1152) & 31;
  int bo = tid / 36864;
  const float2* src = gs + ((size_t)bo * 32 + s) * 288 + kx;
  float ar = 0.f, ai = 0.f;
  #pragma unroll 8
  for (int kz = 0; kz < 24; ++kz) {
    float2 v = src[kz * 12];
    float2 w = tw[kz * 96 + z];
    ar += v.x * w.x - v.y * w.y;
    ai += v.x * w.y + v.y * w.x;
  }
  gz[(((size_t)bo * 32 + s) * 96 + z) * 12 + kx] = make_float2(ar, ai);
}

// a[b][o][s][z][x] = Re(sum_kx Gz e^{+..}) + sum_i ww[o][i] h_bn[b][i][s][z][x] + wb[o]
__global__ __launch_bounds__(256) void k_idftx_fuse(const float2* __restrict__ gz, const float* __restrict__ hsrc,
                             const float* __restrict__ ww, const float* __restrict__ wb,
                             const float2* __restrict__ twxi, const float* __restrict__ sc,
                             int use_bn, float* __restrict__ adst) {
  __shared__ float sh_h[C_ * NX];    // 12 KB, post-BN+leaky
  int blk = blockIdx.x;               // z fastest
  int z = blk % NZ, s = (blk / NZ) % NS, b = blk / (NZ * NS);
  int t = threadIdx.x;
  size_t rowbase = ((size_t)b * C_) * CHS + (size_t)s * (NZ * NX) + (size_t)z * NX;
  float lk = use_bn ? 0.1f : 1.0f;
  for (int i = t; i < C_ * NX; i += 256) {
    int c = i / NX, x = i % NX;
    float v = hsrc[rowbase + (size_t)c * CHS + x];
    float scl = use_bn ? sc[c] : 1.f;
    float shf = use_bn ? sc[32 + c] : 0.f;
    v = v * scl + shf;
    sh_h[i] = v >= 0.f ? v : v * lk;
  }
  __syncthreads();
  int x = t & 127;
  int og = t >> 7;                    // uniform per wave
  if (x >= NX) return;
  float2 tw[KX];
  #pragma unroll
  for (int k = 0; k < KX; ++k) tw[k] = twxi[k * NX + x];
  float acc[16];
  #pragma unroll
  for (int j = 0; j < 16; ++j) {      // o uniform; gz/wb reads -> scalar path
    int o = og * 16 + j;
    float a = wb[o];
    const float2* gp = gz + (((size_t)(b * C_ + o) * NS + s) * NZ + z) * KX;
    #pragma unroll
    for (int k = 0; k < KX; ++k) {
      float2 gv = gp[k];
      a += gv.x * tw[k].x - gv.y * tw[k].y;
    }
    acc[j] = a;
  }
  for (int i = 0; i < C_; ++i) {
    float val = sh_h[i * NX + x];
    #pragma unroll
    for (int j = 0; j < 16; ++j) acc[j] += ww[(og * 16 + j) * C_ + i] * val;  // s_load
  }
  #pragma unroll
  for (int j = 0; j < 16; ++j)
    adst[rowbase + (size_t)(og * 16 + j) * CHS + x] = acc[j];
}

// partial sums of raw a into st[l] (sum[32], sumsq[32])
__global__ void k_bnstats(const float* __restrict__ a, float* __restrict__ st) {
  int bc = blockIdx.x >> 4;           // (b,c) 0..63
  int chunk = blockIdx.x & 15;
  const float4* p = (const float4*)(a + (size_t)bc * CHS + (size_t)chunk * 18432);
  float s = 0.f, s2 = 0.f;
  for (int i = threadIdx.x; i < 4608; i += 256) {
    float4 v = p[i];
    s += v.x + v.y + v.z + v.w;
    s2 += v.x * v.x + v.y * v.y + v.z * v.z + v.w * v.w;
  }
  for (int off = 32; off > 0; off >>= 1) {
    s  += __shfl_down(s, off);
    s2 += __shfl_down(s2, off);
  }
  __shared__ float rs[4], rs2[4];
  if ((threadIdx.x & 63) == 0) { rs[threadIdx.x >> 6] = s; rs2[threadIdx.x >> 6] = s2; }
  __syncthreads();
  if (threadIdx.x == 0) {
    float S = rs[0] + rs[1] + rs[2] + rs[3];
    float S2 = rs2[0] + rs2[1] + rs2[2] + rs2[3];
    int c = bc & 31;
    atomicAdd(&st[c], S);
    atomicAdd(&st[32 + c], S2);
  }
}

// st -> (scale, shift) for this layer
__global__ void k_bnfinal(const float* __restrict__ st, const float* __restrict__ g,
                          const float* __restrict__ bb, float* __restrict__ sc) {
  int c = threadIdx.x;
  if (c >= 32) return;
  const float N = (float)NPTS;
  float mean = st[c] / N;
  float var = st[32 + c] / N - mean * mean;
  float inv = rsqrtf(var + 1e-5f);
  float scale = inv * g[c];
  sc[c] = scale;
  sc[32 + c] = bb[c] - mean * scale;
}

template <int K, int SIN, int M, int SOUT>
__device__ __forceinline__ void mlp_layer(const float* sin_, float* sout,
                                          const float* __restrict__ w,
                                          const float* __restrict__ bias, int p, int q) {
  constexpr int MQ = M / 4;
  float acc[MQ];
  const int m0 = q * MQ;
  #pragma unroll
  for (int j = 0; j < MQ; ++j) acc[j] = 0.f;
  const float* srow = sin_ + p * SIN;
  #pragma unroll 4
  for (int k = 0; k < K; ++k) {
    float av = srow[k];
    const float* wr = w + k * M + m0;
    #pragma unroll
    for (int j = 0; j < MQ; ++j) acc[j] += av * wr[j];
  }
  float* orow = sout + p * SOUT;
  #pragma unroll
  for (int j = 0; j < MQ; ++j) {
    float v = acc[j] + bias[m0 + j];
    orow[m0 + j] = v >= 0.f ? v : 0.1f * v;
  }
}

__global__ __launch_bounds__(256) void k_mlp(
    const float* __restrict__ h, const float* __restrict__ xin,
    const float* __restrict__ sc, int blk0,
    const float* __restrict__ w1, const float* __restrict__ b1,
    const float* __restrict__ w2, const float* __restrict__ b2,
    const float* __restrict__ w3, const float* __restrict__ b3,
    const float* __restrict__ w4, const float* __restrict__ b4,
    const float* __restrict__ w5, const float* __restrict__ b5,
    const float* __restrict__ w7, const float* __restrict__ b7,
    float* __restrict__ out) {
  __shared__ float A[64 * 65];
  __shared__ float Bf[64 * 129];
  int t = threadIdx.x;
  int p = t & 63;
  int q = __builtin_amdgcn_readfirstlane(t >> 6);
  int pt = (blockIdx.x + blk0) * 64 + p;
  int z = (pt / NX) % NZ;
  size_t base = (size_t)(pt / CHS) * C_ * CHS + (pt % CHS);
  #pragma unroll
  for (int i = 0; i < 8; ++i) {
    int c = q * 8 + i;
    float v = h[base + (size_t)c * CHS];
    v = v * sc[c] + sc[32 + c];           // BN(layer3), scalar path
    A[p * 65 + c] = v >= 0.f ? v : 0.1f * v;
  }
  __syncthreads();
  mlp_layer<32, 65, 128, 129>(A, Bf, w1, b1, p, q);   __syncthreads();
  mlp_layer<128, 129, 64, 65>(Bf, A, w2, b2, p, q);   __syncthreads();
  mlp_layer<64, 65, 32, 129>(A, Bf, w3, b3, p, q);    __syncthreads();
  mlp_layer<32, 129, 64, 65>(Bf, A, w4, b4, p, q);    __syncthreads();
  mlp_layer<64, 65, 128, 129>(A, Bf, w5, b5, p, q);   __syncthreads();
  if (q == 0) {
    float acc = b7[0];
    const float* srow = Bf + p * 129;
    #pragma unroll 4
    for (int k = 0; k < 128; ++k) acc += srow[k] * w7[k];
    float T0 = xin[2 * pt + 1];
    float mask = (T0 < 0.01f) ? T0 : 1.0f;
    if (z < 2) mask = 0.f;
    out[pt] = acc * mask;
  }
}

__global__ void k_loss(const float* __restrict__ tau, const float* __restrict__ xin,
                       const float* __restrict__ y, float* __restrict__ loss) {
  int pt = blockIdx.x * 256 + threadIdx.x;
  int x = pt % NX, z = (pt / NX) % NZ;
  float tpx = (x < NX - 1) ? tau[pt + 1] : 0.f;
  float tmx = (x > 0) ? tau[pt - 1] : 0.f;
  float tpz = (z < NZ - 1) ? tau[pt + NX] : 0.f;
  float tmz = (z > 0) ? tau[pt - NX] : 0.f;
  float Tpx = (x < NX - 1) ? xin[2 * (pt + 1) + 1] : 0.f;
  float Tmx = (x > 0) ? xin[2 * (pt - 1) + 1] : 0.f;
  float Tpz = (z < NZ - 1) ? xin[2 * (pt + NX) + 1] : 0.f;
  float Tmz = (z > 0) ? xin[2 * (pt - NX) + 1] : 0.f;
  float dx = (tpx - tmx) * 50.f + (Tpx - Tmx) * 50.f;
  float dz = (tpz - tmz) * 50.f + (Tpz - Tmz) * 50.f;
  loss[pt] = dx * dx + dz * dz - y[pt];
}

extern "C" void kernel_launch(void* const* d_in, const int* in_sizes, int n_in,
                              void* d_out, int out_size, void* d_ws, size_t ws_size,
                              hipStream_t stream) {
  (void)in_sizes; (void)n_in; (void)out_size; (void)ws_size;
  const float* xin    = (const float*)d_in[0];
  const float* y      = (const float*)d_in[1];
  const float* fc0_w  = (const float*)d_in[2];
  const float* fc0_b  = (const float*)d_in[3];
  const float* spec_w = (const float*)d_in[4];
  const float* w_w    = (const float*)d_in[5];
  const float* w_b    = (const float*)d_in[6];
  const float* bn_g   = (const float*)d_in[7];
  const float* bn_b   = (const float*)d_in[8];
  const float* fc1_w  = (const float*)d_in[9];
  const float* fc1_b  = (const float*)d_in[10];
  const float* fc2_w  = (const float*)d_in[11];
  const float* fc2_b  = (const float*)d_in[12];
  const float* fc3_w  = (const float*)d_in[13];
  const float* fc3_b  = (const float*)d_in[14];
  const float* fc4_w  = (const float*)d_in[15];
  const float* fc4_b  = (const float*)d_in[16];
  const float* fc5_w  = (const float*)d_in[17];
  const float* fc5_b  = (const float*)d_in[18];
  const float* fc7_w  = (const float*)d_in[19];
  const float* fc7_b  = (const float*)d_in[20];
  float* ws  = (float*)d_ws;
  float* out = (float*)d_out;

  k_init_tw<<<1, 256, 0, stream>>>(ws);
  k_zero_stats<<<1, 256, 0, stream>>>(ws + OFF_ST);
  k_fc0<<<NPTS / 256, 256, 0, stream>>>(xin, fc0_w, fc0_b, ws + OFF_HA);

  float* hsrc = ws + OFF_HA;
  float* hdst = ws + OFF_HB;
  for (int l = 0; l < 4; ++l) {
    const float* sc_prev = ws + OFF_SC + (size_t)(l - 1) * 64;  // only read if l>0
    int use_bn = (l > 0) ? 1 : 0;
    k_fwd<<<B_ * C_ * NS, 256, 0, stream>>>(hsrc, (float2*)(ws + OFF_FZX),
                                            (const float2*)(ws + OFF_TWXF),
                                            (const float2*)(ws + OFF_TWZF), sc_prev, use_bn);
    k_dfts<<<1152, 256, 0, stream>>>((const float2*)(ws + OFF_FZX), (float2*)(ws + OFF_FS),
                                     (const float2*)(ws + OFF_TWSF));
    k_mix<<<576, 256, 0, stream>>>((const float2*)(ws + OFF_FS), spec_w, l,
                                   (float2*)(ws + OFF_G));
    k_idfts<<<2304, 256, 0, stream>>>((const float2*)(ws + OFF_G), (float2*)(ws + OFF_FZX),
                                      (const float2*)(ws + OFF_TWSI));
    k_idftz<<<9216, 256, 0, stream>>>((const float2*)(ws + OFF_FZX), (float2*)(ws + OFF_FX),
                                      (const float2*)(ws + OFF_TWZI));
    k_idftx_fuse<<<B_ * NS * NZ, 256, 0, stream>>>((const float2*)(ws + OFF_FX), hsrc,
                                                   w_w + (size_t)l * C_ * C_, w_b + (size_t)l * C_,
                                                   (const float2*)(ws + OFF_TWXI), sc_prev,
                                                   use_bn, hdst);
    k_bnstats<<<1024, 256, 0, stream>>>(hdst, ws + OFF_ST + (size_t)l * 64);
    k_bnfinal<<<1, 64, 0, stream>>>(ws + OFF_ST + (size_t)l * 64, bn_g + (size_t)l * C_,
                                    bn_b + (size_t)l * C_, ws + OFF_SC + (size_t)l * 64);
    float* tmp = hsrc; hsrc = hdst; hdst = tmp;
  }

  // k_mlp split into 3 sub-launches: lowers the top-5 visibility threshold so
  // any chain dispatch >~155us will surface in the next profile.
  for (int part = 0; part < 3; ++part) {
    k_mlp<<<3072, 256, 0, stream>>>(hsrc, xin, ws + OFF_SC + 192, part * 3072,
                                    fc1_w, fc1_b, fc2_w, fc2_b, fc3_w, fc3_b,
                                    fc4_w, fc4_b, fc5_w, fc5_b, fc7_w, fc7_b, out);
  }
  k_loss<<<NPTS / 256, 256, 0, stream>>>(out, xin, y, out + NPTS);
}

// Round 6
// 1612.055 us; speedup vs baseline: 1.7816x; 1.7816x over previous
//
#include <hip/hip_runtime.h>
#include <math.h>

constexpr int B_ = 2, C_ = 32, NS = 32, NZ = 96, NX = 96;
constexpr int KS = 16, KZ = 24, KX = 12;          // kept mode counts (s, z, x)
constexpr int NPTS = B_ * NS * NZ * NX;           // 589824
constexpr int CHS  = NS * NZ * NX;                // 294912 (per-channel stride)
constexpr size_t HSIZE = (size_t)B_ * C_ * CHS;   // 18,874,368 floats

constexpr size_t FX_C  = (size_t)B_ * C_ * NS * KX * NZ;  // 2,359,296 cplx (gz)
constexpr size_t FZX_C = (size_t)B_ * C_ * KZ * KX * NS;  //   589,824 cplx (fzx/gs)
constexpr size_t FS_C  = (size_t)B_ * C_ * KS * KZ * KX;  //   294,912 cplx

// workspace offsets (floats). gs overlays FZX, gz overlays FX (sizes match).
constexpr size_t OFF_HA   = 0;
constexpr size_t OFF_HB   = OFF_HA + HSIZE;
constexpr size_t OFF_FX   = OFF_HB + HSIZE;
constexpr size_t OFF_FZX  = OFF_FX + 2 * FX_C;
constexpr size_t OFF_FS   = OFF_FZX + 2 * FZX_C;
constexpr size_t OFF_G    = OFF_FS + 2 * FS_C;
constexpr size_t OFF_ST   = OFF_G + 2 * FS_C;     // 4 layers x (sum[32], sumsq[32])
constexpr size_t OFF_SC   = OFF_ST + 256;         // 4 layers x (scale[32], shift[32])
constexpr size_t OFF_TWXF = OFF_SC + 256;         // [x=96][k=12] cplx, e^{-i}
constexpr size_t OFF_TWZF = OFF_TWXF + 2 * 96 * 12;   // [z=96][k=24]
constexpr size_t OFF_TWSF = OFF_TWZF + 2 * 96 * 24;   // [s=32][k=16], includes 1/294912
constexpr size_t OFF_TWSI = OFF_TWSF + 2 * 32 * 16;   // [k=16][s=32] cplx, e^{+i}
constexpr size_t OFF_TWZI = OFF_TWSI + 2 * 16 * 32;   // [k=24][z=96]
constexpr size_t OFF_TWXI = OFF_TWZI + 2 * 24 * 96;   // [k=12][x=96]

__global__ void k_init_tw(float* ws) {
  const double TWO_PI = 6.283185307179586476925286766559;
  int t = threadIdx.x;
  float2* twxf = (float2*)(ws + OFF_TWXF);
  for (int i = t; i < 96 * 12; i += 256) {
    int x = i / 12, k = i % 12;
    double a = -TWO_PI * (double)((k * x) % 96) / 96.0;
    twxf[i] = make_float2((float)cos(a), (float)sin(a));
  }
  float2* twzf = (float2*)(ws + OFF_TWZF);
  for (int i = t; i < 96 * 24; i += 256) {
    int z = i / 24, k = i % 24;
    double a = -TWO_PI * (double)((k * z) % 96) / 96.0;
    twzf[i] = make_float2((float)cos(a), (float)sin(a));
  }
  float2* twsf = (float2*)(ws + OFF_TWSF);
  const double SC = 1.0 / (double)(NS * NZ * NX);  // fftn norm='forward'
  for (int i = t; i < 32 * 16; i += 256) {
    int s = i / 16, k = i % 16;
    int f = (k < 8) ? k : k + 16;                  // s-modes 0..7, 24..31
    double a = -TWO_PI * (double)((f * s) % 32) / 32.0;
    twsf[i] = make_float2((float)(cos(a) * SC), (float)(sin(a) * SC));
  }
  float2* twsi = (float2*)(ws + OFF_TWSI);
  for (int i = t; i < 16 * 32; i += 256) {
    int k = i / 32, s = i % 32;
    int f = (k < 8) ? k : k + 16;
    double a = TWO_PI * (double)((f * s) % 32) / 32.0;
    twsi[i] = make_float2((float)cos(a), (float)sin(a));
  }
  float2* twzi = (float2*)(ws + OFF_TWZI);
  for (int i = t; i < 24 * 96; i += 256) {
    int k = i / 96, z = i % 96;
    int f = (k < 12) ? k : k + 72;                 // z-modes 0..11, 84..95
    double a = TWO_PI * (double)((f * z) % 96) / 96.0;
    twzi[i] = make_float2((float)cos(a), (float)sin(a));
  }
  float2* twxi = (float2*)(ws + OFF_TWXI);
  for (int i = t; i < 12 * 96; i += 256) {
    int k = i / 96, x = i % 96;
    double a = TWO_PI * (double)((k * x) % 96) / 96.0;
    twxi[i] = make_float2((float)cos(a), (float)sin(a));
  }
}

__global__ void k_zero_stats(float* st) {
  st[threadIdx.x] = 0.f;   // 256 threads, 256 floats
}

// h[b][c][s][z][x] = x0*w[0][c] + x1*w[1][c] + b[c]
__global__ void k_fc0(const float* __restrict__ xin, const float* __restrict__ w,
                      const float* __restrict__ bias, float* __restrict__ h) {
  int pt = blockIdx.x * 256 + threadIdx.x;
  float2 xv = ((const float2*)xin)[pt];
  size_t base = (size_t)(pt / CHS) * C_ * CHS + (pt % CHS);
  for (int c = 0; c < C_; ++c)
    h[base + (size_t)c * CHS] = xv.x * w[c] + xv.y * w[C_ + c] + bias[c];
}

// Fused dftx+dftz. block = (b,c,s). Stage BN(h) plane in LDS (coalesced, +97
// pad), dftx with 6 complex reg-accumulators per thread + SCALAR twiddles
// (half = t>>7 is wave-uniform), dftz with dual accumulators.
// Output fzx[bcs][kz*12+kx] contiguous per block.
__global__ __launch_bounds__(256) void k_fwd(const float* __restrict__ h, float2* __restrict__ fzx,
                      const float2* __restrict__ twxf, const float2* __restrict__ twzf,
                      const float* __restrict__ sc, int use_bn) {
  __shared__ float  sh_h[96 * 97];     // 37.2 KB
  __shared__ float2 sh_fx[96 * 12];    // 9 KB  [z][kx]
  int t = threadIdx.x;
  int bcs = blockIdx.x;               // 2048 = 64 bc * 32 s
  int s = bcs & 31;
  int bc = bcs >> 5;
  int c = bc & 31;
  float scale = use_bn ? sc[c] : 1.f;
  float shift = use_bn ? sc[32 + c] : 0.f;
  float lk = use_bn ? 0.1f : 1.0f;
  const float* hp = h + (size_t)bc * CHS + (size_t)s * (NZ * NX);
  for (int i = t; i < NZ * NX; i += 256) {
    float v = hp[i];                   // coalesced row-major
    v = v * scale + shift;
    v = v >= 0.f ? v : v * lk;
    sh_h[(i / 96) * 97 + (i % 96)] = v;
  }
  __syncthreads();
  // dftx: waves 0-1 -> kx 0..5, waves 2-3 -> kx 6..11; z = t&127 (<96 active)
  {
    int half = __builtin_amdgcn_readfirstlane(t >> 7);   // wave-uniform
    int z = t & 127;
    if (z < 96) {
      float ar[6], ai[6];
      #pragma unroll
      for (int j = 0; j < 6; ++j) { ar[j] = 0.f; ai[j] = 0.f; }
      const float2* twx = twxf + half * 6;
      const float* row = sh_h + z * 97;
      for (int x = 0; x < 96; ++x) {
        float v = row[x];              // 1 ds_read per 12 FMAs
        #pragma unroll
        for (int j = 0; j < 6; ++j) {
          float2 w = twx[x * 12 + j];  // wave-uniform -> s_load (K$-hot)
          ar[j] += v * w.x; ai[j] += v * w.y;
        }
      }
      #pragma unroll
      for (int j = 0; j < 6; ++j)
        sh_fx[z * 12 + half * 6 + j] = make_float2(ar[j], ai[j]);
    }
  }
  __syncthreads();
  // dftz: item = (kz,kx), 288 items; dual accumulators, tw L1-hot vector loads
  float2* outp = fzx + (size_t)bcs * 288;
  for (int it = t; it < 288; it += 256) {
    int kx = it % 12, kz = it / 12;
    float ar0 = 0.f, ai0 = 0.f, ar1 = 0.f, ai1 = 0.f;
    for (int z = 0; z < 96; z += 2) {
      float2 v0 = sh_fx[z * 12 + kx];
      float2 w0 = twzf[z * 24 + kz];
      float2 v1 = sh_fx[(z + 1) * 12 + kx];
      float2 w1 = twzf[(z + 1) * 24 + kz];
      ar0 += v0.x * w0.x - v0.y * w0.y;
      ai0 += v0.x * w0.y + v0.y * w0.x;
      ar1 += v1.x * w1.x - v1.y * w1.y;
      ai1 += v1.x * w1.y + v1.y * w1.x;
    }
    outp[it] = make_float2(ar0 + ar1, ai0 + ai1);   // coalesced
  }
}

// Fs[bc][ks*288+kzkx] = sum_s Fzx[bc][s][kzkx] * tw; thread per output.
__global__ __launch_bounds__(256) void k_dfts(const float2* __restrict__ fzx, float2* __restrict__ fs,
                       const float2* __restrict__ tw) {
  int tid = blockIdx.x * 256 + threadIdx.x;   // 294,912
  int kzkx = tid % 288;
  int ks = (tid / 288) & 15;
  int bc = tid / 4608;
  const float2* src = fzx + (size_t)bc * (32 * 288) + kzkx;
  float ar = 0.f, ai = 0.f;
  #pragma unroll 8
  for (int s = 0; s < 32; ++s) {
    float2 v = src[s * 288];
    float2 w = tw[s * 16 + ks];
    ar += v.x * w.x - v.y * w.y;
    ai += v.x * w.y + v.y * w.x;
  }
  fs[(size_t)bc * 4608 + ks * 288 + kzkx] = make_float2(ar, ai);
}

// G[b][o][fidx] = sum_i Fs[b][i][fidx] * w[l,q,i,o,mode]; lanes = consecutive modes
__global__ __launch_bounds__(256) void k_mix(const float2* __restrict__ fs, const float* __restrict__ spec,
                      int l, float2* __restrict__ g) {
  int tid = blockIdx.x * 256 + threadIdx.x;   // 147,456 = 4q * 32o * 1152m
  int m = tid % 1152;
  int o = (tid / 1152) & 31;
  int q = tid / 36864;
  int m1 = m / 144, r = m - m1 * 144, m2 = r / 12, m3 = r - m2 * 12;
  int ks = m1 + (q & 1) * 8;
  int kz = m2 + ((q >> 1) & 1) * 12;
  int fidx = (ks * KZ + kz) * KX + m3;
  const float2* w2 = (const float2*)spec;
  size_t widx = ((size_t)(l * 4 + q) * 1024 + o) * 1152 + m;   // + i*36864 per i
  const float2* f0 = fs + fidx;                                 // + i*4608 per i
  const float2* f1 = fs + (size_t)C_ * 4608 + fidx;
  float a0r = 0.f, a0i = 0.f, a1r = 0.f, a1i = 0.f;
  #pragma unroll 4
  for (int i = 0; i < C_; ++i) {
    float2 w = w2[widx];  widx += 36864;
    float2 v0 = f0[(size_t)i * 4608];
    float2 v1 = f1[(size_t)i * 4608];
    a0r += v0.x * w.x - v0.y * w.y;  a0i += v0.x * w.y + v0.y * w.x;
    a1r += v1.x * w.x - v1.y * w.y;  a1i += v1.x * w.y + v1.y * w.x;
  }
  g[(size_t)o * 4608 + fidx] = make_float2(a0r, a0i);
  g[(size_t)(C_ + o) * 4608 + fidx] = make_float2(a1r, a1i);
}

// Gs[bo][s][kzkx] = sum_ks G[bo][ks*288+kzkx] * tw; thread per output.
__global__ __launch_bounds__(256) void k_idfts(const float2* __restrict__ g, float2* __restrict__ gs,
                        const float2* __restrict__ tw) {
  int tid = blockIdx.x * 256 + threadIdx.x;   // 589,824
  int kzkx = tid % 288;
  int s = (tid / 288) & 31;
  int bo = tid / 9216;
  const float2* src = g + (size_t)bo * 4608 + kzkx;
  float ar = 0.f, ai = 0.f;
  #pragma unroll
  for (int ks = 0; ks < 16; ++ks) {
    float2 v = src[ks * 288];
    float2 w = tw[ks * 32 + s];
    ar += v.x * w.x - v.y * w.y;
    ai += v.x * w.y + v.y * w.x;
  }
  gs[((size_t)bo * 32 + s) * 288 + kzkx] = make_float2(ar, ai);
}

// Gz[bo][s][z][kx] = sum_kz Gs[bo][s][kz*12+kx] * tw; thread per output.
__global__ __launch_bounds__(256) void k_idftz(const float2* __restrict__ gs, float2* __restrict__ gz,
                        const float2* __restrict__ tw) {
  int tid = blockIdx.x * 256 + threadIdx.x;   // 2,359,296
  int kx = tid % 12;
  int z = (tid / 12) % 96;
  int s = (tid / 1152) & 31;
  int bo = tid / 36864;
  const float2* src = gs + ((size_t)bo * 32 + s) * 288 + kx;
  float ar = 0.f, ai = 0.f;
  #pragma unroll 8
  for (int kz = 0; kz < 24; ++kz) {
    float2 v = src[kz * 12];
    float2 w = tw[kz * 96 + z];
    ar += v.x * w.x - v.y * w.y;
    ai += v.x * w.y + v.y * w.x;
  }
  gz[(((size_t)bo * 32 + s) * 96 + z) * 12 + kx] = make_float2(ar, ai);
}

// a[b][o][s][z][x] = Re(sum_kx Gz e^{+..}) + sum_i ww[o][i] h_bn[b][i][s][z][x] + wb[o]
// gz staged in LDS (cooperative, once per block); ww/wb on the scalar path
// (og provably wave-uniform via readfirstlane).
__global__ __launch_bounds__(256) void k_idftx_fuse(const float2* __restrict__ gz, const float* __restrict__ hsrc,
                             const float* __restrict__ ww, const float* __restrict__ wb,
                             const float2* __restrict__ twxi, const float* __restrict__ sc,
                             int use_bn, float* __restrict__ adst) {
  __shared__ float  sh_h[C_ * NX];    // 12 KB, post-BN+leaky
  __shared__ float2 sh_g[C_ * KX];    // 3 KB, this (b,s,z)'s 32x12 gz fragments
  int blk = blockIdx.x;               // z fastest
  int z = blk % NZ, s = (blk / NZ) % NS, b = blk / (NZ * NS);
  int t = threadIdx.x;
  size_t rowbase = ((size_t)b * C_) * CHS + (size_t)s * (NZ * NX) + (size_t)z * NX;
  float lk = use_bn ? 0.1f : 1.0f;
  for (int i = t; i < C_ * NX; i += 256) {
    int c = i / NX, x = i % NX;
    float v = hsrc[rowbase + (size_t)c * CHS + x];
    float scl = use_bn ? sc[c] : 1.f;
    float shf = use_bn ? sc[32 + c] : 0.f;
    v = v * scl + shf;
    sh_h[i] = v >= 0.f ? v : v * lk;
  }
  // stage gz: 384 float2; thread i -> (o = i/12, kx = i%12); 96B contiguous runs
  for (int i = t; i < C_ * KX; i += 256) {
    int o = i / KX, kx = i % KX;
    sh_g[i] = gz[(((size_t)(b * C_ + o) * NS + s) * NZ + z) * KX + kx];
  }
  __syncthreads();
  int x = t & 127;
  int og = __builtin_amdgcn_readfirstlane(t >> 7);   // wave-uniform
  if (x >= NX) return;
  float2 tw[KX];
  #pragma unroll
  for (int k = 0; k < KX; ++k) tw[k] = twxi[k * NX + x];
  float acc[16];
  #pragma unroll
  for (int j = 0; j < 16; ++j) {
    int o = og * 16 + j;
    float a = wb[o];                                  // s_load
    const float2* gp = sh_g + o * KX;                 // LDS broadcast (free)
    #pragma unroll
    for (int k = 0; k < KX; ++k) {
      float2 gv = gp[k];
      a += gv.x * tw[k].x - gv.y * tw[k].y;
    }
    acc[j] = a;
  }
  for (int i = 0; i < C_; ++i) {
    float val = sh_h[i * NX + x];
    #pragma unroll
    for (int j = 0; j < 16; ++j) acc[j] += ww[(og * 16 + j) * C_ + i] * val;  // s_load
  }
  #pragma unroll
  for (int j = 0; j < 16; ++j)
    adst[rowbase + (size_t)(og * 16 + j) * CHS + x] = acc[j];
}

// partial sums of raw a into st[l] (sum[32], sumsq[32])
__global__ void k_bnstats(const float* __restrict__ a, float* __restrict__ st) {
  int bc = blockIdx.x >> 4;           // (b,c) 0..63
  int chunk = blockIdx.x & 15;
  const float4* p = (const float4*)(a + (size_t)bc * CHS + (size_t)chunk * 18432);
  float s = 0.f, s2 = 0.f;
  for (int i = threadIdx.x; i < 4608; i += 256) {
    float4 v = p[i];
    s += v.x + v.y + v.z + v.w;
    s2 += v.x * v.x + v.y * v.y + v.z * v.z + v.w * v.w;
  }
  for (int off = 32; off > 0; off >>= 1) {
    s  += __shfl_down(s, off);
    s2 += __shfl_down(s2, off);
  }
  __shared__ float rs[4], rs2[4];
  if ((threadIdx.x & 63) == 0) { rs[threadIdx.x >> 6] = s; rs2[threadIdx.x >> 6] = s2; }
  __syncthreads();
  if (threadIdx.x == 0) {
    float S = rs[0] + rs[1] + rs[2] + rs[3];
    float S2 = rs2[0] + rs2[1] + rs2[2] + rs2[3];
    int c = bc & 31;
    atomicAdd(&st[c], S);
    atomicAdd(&st[32 + c], S2);
  }
}

// st -> (scale, shift) for this layer
__global__ void k_bnfinal(const float* __restrict__ st, const float* __restrict__ g,
                          const float* __restrict__ bb, float* __restrict__ sc) {
  int c = threadIdx.x;
  if (c >= 32) return;
  const float N = (float)NPTS;
  float mean = st[c] / N;
  float var = st[32 + c] / N - mean * mean;
  float inv = rsqrtf(var + 1e-5f);
  float scale = inv * g[c];
  sc[c] = scale;
  sc[32 + c] = bb[c] - mean * scale;
}

template <int K, int SIN, int M, int SOUT>
__device__ __forceinline__ void mlp_layer(const float* sin_, float* sout,
                                          const float* __restrict__ w,
                                          const float* __restrict__ bias, int p, int q) {
  constexpr int MQ = M / 4;
  float acc[MQ];
  const int m0 = q * MQ;
  #pragma unroll
  for (int j = 0; j < MQ; ++j) acc[j] = 0.f;
  const float* srow = sin_ + p * SIN;
  #pragma unroll 4
  for (int k = 0; k < K; ++k) {
    float av = srow[k];
    const float* wr = w + k * M + m0;
    #pragma unroll
    for (int j = 0; j < MQ; ++j) acc[j] += av * wr[j];
  }
  float* orow = sout + p * SOUT;
  #pragma unroll
  for (int j = 0; j < MQ; ++j) {
    float v = acc[j] + bias[m0 + j];
    orow[m0 + j] = v >= 0.f ? v : 0.1f * v;
  }
}

__global__ __launch_bounds__(256) void k_mlp(
    const float* __restrict__ h, const float* __restrict__ xin,
    const float* __restrict__ sc, int blk0,
    const float* __restrict__ w1, const float* __restrict__ b1,
    const float* __restrict__ w2, const float* __restrict__ b2,
    const float* __restrict__ w3, const float* __restrict__ b3,
    const float* __restrict__ w4, const float* __restrict__ b4,
    const float* __restrict__ w5, const float* __restrict__ b5,
    const float* __restrict__ w7, const float* __restrict__ b7,
    float* __restrict__ out) {
  __shared__ float A[64 * 65];
  __shared__ float Bf[64 * 129];
  int t = threadIdx.x;
  int p = t & 63;
  int q = __builtin_amdgcn_readfirstlane(t >> 6);
  int pt = (blockIdx.x + blk0) * 64 + p;
  int z = (pt / NX) % NZ;
  size_t base = (size_t)(pt / CHS) * C_ * CHS + (pt % CHS);
  #pragma unroll
  for (int i = 0; i < 8; ++i) {
    int c = q * 8 + i;
    float v = h[base + (size_t)c * CHS];
    v = v * sc[c] + sc[32 + c];           // BN(layer3), scalar path
    A[p * 65 + c] = v >= 0.f ? v : 0.1f * v;
  }
  __syncthreads();
  mlp_layer<32, 65, 128, 129>(A, Bf, w1, b1, p, q);   __syncthreads();
  mlp_layer<128, 129, 64, 65>(Bf, A, w2, b2, p, q);   __syncthreads();
  mlp_layer<64, 65, 32, 129>(A, Bf, w3, b3, p, q);    __syncthreads();
  mlp_layer<32, 129, 64, 65>(Bf, A, w4, b4, p, q);    __syncthreads();
  mlp_layer<64, 65, 128, 129>(A, Bf, w5, b5, p, q);   __syncthreads();
  if (q == 0) {
    float acc = b7[0];
    const float* srow = Bf + p * 129;
    #pragma unroll 4
    for (int k = 0; k < 128; ++k) acc += srow[k] * w7[k];
    float T0 = xin[2 * pt + 1];
    float mask = (T0 < 0.01f) ? T0 : 1.0f;
    if (z < 2) mask = 0.f;
    out[pt] = acc * mask;
  }
}

__global__ void k_loss(const float* __restrict__ tau, const float* __restrict__ xin,
                       const float* __restrict__ y, float* __restrict__ loss) {
  int pt = blockIdx.x * 256 + threadIdx.x;
  int x = pt % NX, z = (pt / NX) % NZ;
  float tpx = (x < NX - 1) ? tau[pt + 1] : 0.f;
  float tmx = (x > 0) ? tau[pt - 1] : 0.f;
  float tpz = (z < NZ - 1) ? tau[pt + NX] : 0.f;
  float tmz = (z > 0) ? tau[pt - NX] : 0.f;
  float Tpx = (x < NX - 1) ? xin[2 * (pt + 1) + 1] : 0.f;
  float Tmx = (x > 0) ? xin[2 * (pt - 1) + 1] : 0.f;
  float Tpz = (z < NZ - 1) ? xin[2 * (pt + NX) + 1] : 0.f;
  float Tmz = (z > 0) ? xin[2 * (pt - NX) + 1] : 0.f;
  float dx = (tpx - tmx) * 50.f + (Tpx - Tmx) * 50.f;
  float dz = (tpz - tmz) * 50.f + (Tpz - Tmz) * 50.f;
  loss[pt] = dx * dx + dz * dz - y[pt];
}

extern "C" void kernel_launch(void* const* d_in, const int* in_sizes, int n_in,
                              void* d_out, int out_size, void* d_ws, size_t ws_size,
                              hipStream_t stream) {
  (void)in_sizes; (void)n_in; (void)out_size; (void)ws_size;
  const float* xin    = (const float*)d_in[0];
  const float* y      = (const float*)d_in[1];
  const float* fc0_w  = (const float*)d_in[2];
  const float* fc0_b  = (const float*)d_in[3];
  const float* spec_w = (const float*)d_in[4];
  const float* w_w    = (const float*)d_in[5];
  const float* w_b    = (const float*)d_in[6];
  const float* bn_g   = (const float*)d_in[7];
  const float* bn_b   = (const float*)d_in[8];
  const float* fc1_w  = (const float*)d_in[9];
  const float* fc1_b  = (const float*)d_in[10];
  const float* fc2_w  = (const float*)d_in[11];
  const float* fc2_b  = (const float*)d_in[12];
  const float* fc3_w  = (const float*)d_in[13];
  const float* fc3_b  = (const float*)d_in[14];
  const float* fc4_w  = (const float*)d_in[15];
  const float* fc4_b  = (const float*)d_in[16];
  const float* fc5_w  = (const float*)d_in[17];
  const float* fc5_b  = (const float*)d_in[18];
  const float* fc7_w  = (const float*)d_in[19];
  const float* fc7_b  = (const float*)d_in[20];
  float* ws  = (float*)d_ws;
  float* out = (float*)d_out;

  k_init_tw<<<1, 256, 0, stream>>>(ws);
  k_zero_stats<<<1, 256, 0, stream>>>(ws + OFF_ST);
  k_fc0<<<NPTS / 256, 256, 0, stream>>>(xin, fc0_w, fc0_b, ws + OFF_HA);

  float* hsrc = ws + OFF_HA;
  float* hdst = ws + OFF_HB;
  for (int l = 0; l < 4; ++l) {
    const float* sc_prev = ws + OFF_SC + (size_t)(l - 1) * 64;  // only read if l>0
    int use_bn = (l > 0) ? 1 : 0;
    k_fwd<<<B_ * C_ * NS, 256, 0, stream>>>(hsrc, (float2*)(ws + OFF_FZX),
                                            (const float2*)(ws + OFF_TWXF),
                                            (const float2*)(ws + OFF_TWZF), sc_prev, use_bn);
    k_dfts<<<1152, 256, 0, stream>>>((const float2*)(ws + OFF_FZX), (float2*)(ws + OFF_FS),
                                     (const float2*)(ws + OFF_TWSF));
    k_mix<<<576, 256, 0, stream>>>((const float2*)(ws + OFF_FS), spec_w, l,
                                   (float2*)(ws + OFF_G));
    k_idfts<<<2304, 256, 0, stream>>>((const float2*)(ws + OFF_G), (float2*)(ws + OFF_FZX),
                                      (const float2*)(ws + OFF_TWSI));
    k_idftz<<<9216, 256, 0, stream>>>((const float2*)(ws + OFF_FZX), (float2*)(ws + OFF_FX),
                                      (const float2*)(ws + OFF_TWZI));
    k_idftx_fuse<<<B_ * NS * NZ, 256, 0, stream>>>((const float2*)(ws + OFF_FX), hsrc,
                                                   w_w + (size_t)l * C_ * C_, w_b + (size_t)l * C_,
                                                   (const float2*)(ws + OFF_TWXI), sc_prev,
                                                   use_bn, hdst);
    k_bnstats<<<1024, 256, 0, stream>>>(hdst, ws + OFF_ST + (size_t)l * 64);
    k_bnfinal<<<1, 64, 0, stream>>>(ws + OFF_ST + (size_t)l * 64, bn_g + (size_t)l * C_,
                                    bn_b + (size_t)l * C_, ws + OFF_SC + (size_t)l * 64);
    float* tmp = hsrc; hsrc = hdst; hdst = tmp;
  }

  // k_mlp split into 3 sub-launches keeps the top-5 visibility threshold low.
  for (int part = 0; part < 3; ++part) {
    k_mlp<<<3072, 256, 0, stream>>>(hsrc, xin, ws + OFF_SC + 192, part * 3072,
                                    fc1_w, fc1_b, fc2_w, fc2_b, fc3_w, fc3_b,
                                    fc4_w, fc4_b, fc5_w, fc5_b, fc7_w, fc7_b, out);
  }
  k_loss<<<NPTS / 256, 256, 0, stream>>>(out, xin, y, out + NPTS);
}